// Round 1
// 3658.826 us; speedup vs baseline: 1.0608x; 1.0608x over previous
//
#include <hip/hip_runtime.h>

// ---------------------------------------------------------------------------
// StyleTransformerEncoderBlock (Swin shifted-window, 3 streams) on gfx950.
// Round 1: m97-style GEMM core (global_load_lds width-16 both operands where
// bf16, bijective XCD swizzle), window-order MLP fed by bf16 Y written in the
// out-projection epilogue. Per-stream interleave so workspace regions reuse:
//   Qb region: Q -> V -> Y      Kb region: K -> O -> hidden chunk
//   Pb region: softmax probs (persistent across streams)
// Workspace (u16 elems), 218,103,808 bytes total:
//   [0      .. 8388608 )  transposed bf16 weights
//   [8388608.. 41943040)  Q / V / Y
//   [41943040..75497472)  K / O / hidden (16384x2048 chunk)
//   [75497472..109051904) P
// ---------------------------------------------------------------------------

typedef unsigned short u16;
typedef unsigned int   u32;
typedef __attribute__((ext_vector_type(8))) short shortx8;
typedef __attribute__((ext_vector_type(4))) float floatx4;

__device__ __forceinline__ u16 f2bu(float f) {            // fp32 -> bf16 (RNE)
  u32 b = __builtin_bit_cast(u32, f);
  b += 0x7fffu + ((b >> 16) & 1u);
  return (u16)(b >> 16);
}
__device__ __forceinline__ float bu2f(u32 lo16) {         // bf16 -> fp32
  u32 b = (lo16 & 0xffffu) << 16;
  return __builtin_bit_cast(float, b);
}
__device__ __forceinline__ u32 pk2(float a, float b) {
  return (u32)f2bu(a) | ((u32)f2bu(b) << 16);
}
__device__ __forceinline__ uint4 pack8(float4 a, float4 b) {
  uint4 u;
  u.x = pk2(a.x, a.y); u.y = pk2(a.z, a.w);
  u.z = pk2(b.x, b.y); u.w = pk2(b.z, b.w);
  return u;
}
// window-token t -> original row (roll(-4,-4) gather == window-reverse scatter)
__device__ __forceinline__ int gmap(int t) {
  int win = t >> 6, n = t & 63;
  int b = win >> 6, wy = (win >> 3) & 7, wx = win & 7;
  int r = (wy * 8 + (n >> 3) + 4) & 63;
  int c = (wx * 8 + (n & 7) + 4) & 63;
  return (b << 12) + (r << 6) + c;
}

// async global -> LDS, 16 B per lane. LDS dest must be wave-uniform.
__device__ __forceinline__ void gload16(const void* g, void* l) {
  __builtin_amdgcn_global_load_lds(
      (const __attribute__((address_space(1))) void*)g,
      (__attribute__((address_space(3))) void*)l, 16, 0, 0);
}

// ---------------- weight transpose + bf16 cast: W[K][N] -> Wt[N][K] ----------
__global__ void transpose_cvt(const float* __restrict__ src, u16* __restrict__ dst,
                              int K, int N) {
  __shared__ float tile[32][33];
  int n0 = blockIdx.x * 32, k0 = blockIdx.y * 32;
  int tx = threadIdx.x, ty = threadIdx.y;
#pragma unroll
  for (int i = 0; i < 32; i += 8)
    tile[ty + i][tx] = src[(size_t)(k0 + ty + i) * N + n0 + tx];
  __syncthreads();
#pragma unroll
  for (int i = 0; i < 32; i += 8)
    dst[(size_t)(n0 + ty + i) * K + k0 + tx] = f2bu(tile[tx][ty + i]);
}

// ---------------- generic 128x128 bf16 MFMA GEMM -----------------------------
// AMODE: 0 = fp32 src rows gathered via gmap (window partition fused, pack8)
//        2 = bf16 src rows direct (async global_load_lds staging)
// EPI:   0 = Q/K store (N=1024; q scaled by 1/8 + bq, k + bk) -> (win,h,n,d)
//        1 = V store (+bias) -> (win,h,n,d)
//        2 = out-proj: +bias, y = resid[gmap]+val; outf[gmap]=y (fp32) AND
//            outb0[row*512+col]=bf16(y)  (window-order MLP input)
//        3 = MLP1: relu(+bias) -> bf16 hidden [row][2048]
//        4 = MLP2: +bias, outf[gmap(row+rowoff)*512+col] += val
// NBX = grid width in 128-col tiles (compile-time). 1-D launch, nwg % 8 == 0.
template <int AMODE, int EPI, int NBX>
__global__ __launch_bounds__(256) void gemm_k(
    const void* __restrict__ Aany, int lda,
    const u16* __restrict__ Bt, int K,
    const float* __restrict__ bias0, const float* __restrict__ bias1,
    const float* __restrict__ resid,
    float* __restrict__ outf,
    u16* __restrict__ outb0, u16* __restrict__ outb1, int rowoff) {
  constexpr int LDA = (AMODE == 0) ? 72 : 64;   // pad only the pack8 path
  __shared__ __align__(16) u16 lA[128][LDA];
  __shared__ __align__(16) u16 lB[128][64];
  const int tid = threadIdx.x;
  const int lane = tid & 63;
  const int wv = tid >> 6;
  const int wm = wv >> 1, wn = wv & 1;          // 2x2 waves, 64x64 each
  const int m16 = lane & 15, qd = lane >> 4;

  // bijective XCD swizzle: each XCD gets a contiguous chunk of row-major tiles
  const int nwg = gridDim.x;
  const int lid = ((blockIdx.x & 7) * (nwg >> 3)) + (blockIdx.x >> 3);
  const int by = lid / NBX, bx = lid - by * NBX;
  const int row0 = by * 128, col0 = bx * 128;

  // B staging: always bf16, async direct-to-LDS. One instr = 1 KiB = 8 rows.
  const u16* bsrc = Bt + (size_t)(col0 + wv * 32 + (lane >> 3)) * K + (lane & 7) * 8;

  // A staging
  const float* af = (const float*)Aany;
  const u16*   ab = (const u16*)Aany;
  const int sr = tid >> 1;                      // pack8 staging row
  const int sc = (tid & 1) << 5;                // pack8 staging col 0/32
  size_t aoff = 0;
  const u16* asrc = nullptr;
  if constexpr (AMODE == 0) aoff = (size_t)gmap(row0 + sr) * lda;
  else asrc = ab + (size_t)(row0 + wv * 32 + (lane >> 3)) * lda + (lane & 7) * 8;

  floatx4 acc[4][4];
#pragma unroll
  for (int i = 0; i < 4; ++i)
#pragma unroll
    for (int j = 0; j < 4; ++j)
#pragma unroll
      for (int r = 0; r < 4; ++r) acc[i][j][r] = 0.f;

  for (int k0 = 0; k0 < K; k0 += 64) {
    if constexpr (AMODE == 0) {
      const float* p = af + aoff + k0 + sc;
      float4 f0 = *(const float4*)(p + 0);
      float4 f1 = *(const float4*)(p + 4);
      float4 f2 = *(const float4*)(p + 8);
      float4 f3 = *(const float4*)(p + 12);
      *(uint4*)&lA[sr][sc + 0] = pack8(f0, f1);
      *(uint4*)&lA[sr][sc + 8] = pack8(f2, f3);
      f0 = *(const float4*)(p + 16);
      f1 = *(const float4*)(p + 20);
      f2 = *(const float4*)(p + 24);
      f3 = *(const float4*)(p + 28);
      *(uint4*)&lA[sr][sc + 16] = pack8(f0, f1);
      *(uint4*)&lA[sr][sc + 24] = pack8(f2, f3);
    } else {
#pragma unroll
      for (int t = 0; t < 4; ++t)
        gload16(asrc + (size_t)(k0 + t * 8 * lda), &lA[wv * 32 + t * 8][0]);
    }
#pragma unroll
    for (int t = 0; t < 4; ++t)
      gload16(bsrc + (size_t)(k0 + t * 8 * K), &lB[wv * 32 + t * 8][0]);
    __syncthreads();
#pragma unroll
    for (int kk = 0; kk < 64; kk += 32) {
      shortx8 a[4], b[4];
#pragma unroll
      for (int i = 0; i < 4; ++i)
        a[i] = *(const shortx8*)&lA[wm * 64 + i * 16 + m16][kk + qd * 8];
#pragma unroll
      for (int j = 0; j < 4; ++j)
        b[j] = *(const shortx8*)&lB[wn * 64 + j * 16 + m16][kk + qd * 8];
#pragma unroll
      for (int i = 0; i < 4; ++i)
#pragma unroll
        for (int j = 0; j < 4; ++j)
          acc[i][j] = __builtin_amdgcn_mfma_f32_16x16x32_bf16(a[i], b[j], acc[i][j], 0, 0, 0);
    }
    __syncthreads();
  }

#pragma unroll
  for (int i = 0; i < 4; ++i) {
#pragma unroll
    for (int j = 0; j < 4; ++j) {
#pragma unroll
      for (int rr = 0; rr < 4; ++rr) {
        int row = row0 + wm * 64 + i * 16 + qd * 4 + rr;
        int col = col0 + wn * 64 + j * 16 + m16;
        float v = acc[i][j][rr];
        if constexpr (EPI == 0) {
          int mat = col >> 9, cc = col & 511;
          float val = mat == 0 ? (v + bias0[cc]) * 0.125f : (v + bias1[cc]);
          int win = row >> 6, n = row & 63, hh = cc >> 6, dd = cc & 63;
          size_t dst = (((size_t)(win * 8 + hh) * 64 + n) * 64) + dd;
          (mat ? outb1 : outb0)[dst] = f2bu(val);
        } else if constexpr (EPI == 1) {
          float val = v + bias0[col];
          int win = row >> 6, n = row & 63, hh = col >> 6, dd = col & 63;
          outb0[(((size_t)(win * 8 + hh) * 64 + n) * 64) + dd] = f2bu(val);
        } else if constexpr (EPI == 2) {
          float val = v + bias0[col];
          size_t g = (size_t)gmap(row) * 512 + col;
          float y = resid[g] + val;
          outf[g] = y;
          outb0[(size_t)row * 512 + col] = f2bu(y);
        } else if constexpr (EPI == 3) {
          float val = fmaxf(v + bias0[col], 0.f);
          outb0[(size_t)row * 2048 + col] = f2bu(val);
        } else {
          float val = v + bias0[col];
          size_t g = (size_t)gmap(row + rowoff) * 512 + col;
          outf[g] += val;
        }
      }
    }
  }
}

// ---------------- attention: S = q k^T + rpb + mask ; P = softmax(S) ---------
__global__ __launch_bounds__(256) void attn_softmax(
    const u16* __restrict__ Qb, const u16* __restrict__ Kb,
    const float* __restrict__ rpb, u16* __restrict__ Pb) {
  __shared__ float lq[64][65], lk[64][65], S[64][65];
  __shared__ float rmax[64], rsum[64];
  int bid = blockIdx.x;                 // = win*8 + h
  int h = bid & 7, winb = (bid >> 3) & 63;
  int tid = threadIdx.x;
  int r = tid >> 2, q4 = tid & 3;

  const u16* qt = Qb + (size_t)bid * 4096 + r * 64 + q4 * 16;
  const u16* kt = Kb + (size_t)bid * 4096 + r * 64 + q4 * 16;
  uint4 a0 = *(const uint4*)qt, a1 = *(const uint4*)(qt + 8);
  uint4 b0 = *(const uint4*)kt, b1 = *(const uint4*)(kt + 8);
  {
    float* d = &lq[r][q4 * 16];
    d[0] = bu2f(a0.x); d[1] = bu2f(a0.x >> 16); d[2] = bu2f(a0.y); d[3] = bu2f(a0.y >> 16);
    d[4] = bu2f(a0.z); d[5] = bu2f(a0.z >> 16); d[6] = bu2f(a0.w); d[7] = bu2f(a0.w >> 16);
    d[8] = bu2f(a1.x); d[9] = bu2f(a1.x >> 16); d[10] = bu2f(a1.y); d[11] = bu2f(a1.y >> 16);
    d[12] = bu2f(a1.z); d[13] = bu2f(a1.z >> 16); d[14] = bu2f(a1.w); d[15] = bu2f(a1.w >> 16);
    float* e = &lk[r][q4 * 16];
    e[0] = bu2f(b0.x); e[1] = bu2f(b0.x >> 16); e[2] = bu2f(b0.y); e[3] = bu2f(b0.y >> 16);
    e[4] = bu2f(b0.z); e[5] = bu2f(b0.z >> 16); e[6] = bu2f(b0.w); e[7] = bu2f(b0.w >> 16);
    e[8] = bu2f(b1.x); e[9] = bu2f(b1.x >> 16); e[10] = bu2f(b1.y); e[11] = bu2f(b1.y >> 16);
    e[12] = bu2f(b1.z); e[13] = bu2f(b1.z >> 16); e[14] = bu2f(b1.w); e[15] = bu2f(b1.w >> 16);
  }
  __syncthreads();

  int n = r, mb = q4 * 16;
  float sv[16];
#pragma unroll
  for (int mm = 0; mm < 16; ++mm) sv[mm] = 0.f;
  for (int kk = 0; kk < 64; ++kk) {
    float qv = lq[n][kk];
#pragma unroll
    for (int mm = 0; mm < 16; ++mm) sv[mm] += qv * lk[mb + mm][kk];
  }
  int wy = winb >> 3, wx = winb & 7;
  int grn = wy * 8 + (n >> 3), gcn = wx * 8 + (n & 7);
  int ridn = (grn < 56 ? 0 : (grn < 60 ? 1 : 2)) * 3 + (gcn < 56 ? 0 : (gcn < 60 ? 1 : 2));
#pragma unroll
  for (int mm = 0; mm < 16; ++mm) {
    int m = mb + mm;
    int dy = (n >> 3) - (m >> 3) + 7, dx = (n & 7) - (m & 7) + 7;
    float bias = rpb[(dy * 15 + dx) * 8 + h];
    int grm = wy * 8 + (m >> 3), gcm = wx * 8 + (m & 7);
    int ridm = (grm < 56 ? 0 : (grm < 60 ? 1 : 2)) * 3 + (gcm < 56 ? 0 : (gcm < 60 ? 1 : 2));
    S[n][m] = sv[mm] + bias + (ridm == ridn ? 0.f : -100.f);
  }
  __syncthreads();
  if (tid < 64) {
    float mx = -1e30f;
    for (int m = 0; m < 64; ++m) mx = fmaxf(mx, S[tid][m]);
    float sum = 0.f;
    for (int m = 0; m < 64; ++m) sum += __expf(S[tid][m] - mx);
    rmax[tid] = mx; rsum[tid] = 1.f / sum;
  }
  __syncthreads();
  float mx = rmax[r], is = rsum[r];
  float p[16];
#pragma unroll
  for (int i = 0; i < 16; ++i) p[i] = __expf(S[r][mb + i] - mx) * is;
  uint4 o0, o1;
  o0.x = pk2(p[0], p[1]); o0.y = pk2(p[2], p[3]); o0.z = pk2(p[4], p[5]); o0.w = pk2(p[6], p[7]);
  o1.x = pk2(p[8], p[9]); o1.y = pk2(p[10], p[11]); o1.z = pk2(p[12], p[13]); o1.w = pk2(p[14], p[15]);
  u16* dst = Pb + (size_t)bid * 4096 + r * 64 + mb;
  *(uint4*)dst = o0; *(uint4*)(dst + 8) = o1;
}

// ---------------- attention: O = P V  (per win,head) -------------------------
__global__ __launch_bounds__(256) void attn_av(
    const u16* __restrict__ Pb, const u16* __restrict__ Vb, u16* __restrict__ Ob) {
  __shared__ float lP[64][68], lv[64][68];
  int bid = blockIdx.x;
  int win = bid >> 3, h = bid & 7;
  int tid = threadIdx.x, r = tid >> 2, q4 = tid & 3;

  const u16* pt = Pb + (size_t)bid * 4096 + r * 64 + q4 * 16;
  const u16* vt = Vb + (size_t)bid * 4096 + r * 64 + q4 * 16;
  uint4 a0 = *(const uint4*)pt, a1 = *(const uint4*)(pt + 8);
  uint4 b0 = *(const uint4*)vt, b1 = *(const uint4*)(vt + 8);
  {
    float4* f = (float4*)&lP[r][q4 * 16];
    f[0] = make_float4(bu2f(a0.x), bu2f(a0.x >> 16), bu2f(a0.y), bu2f(a0.y >> 16));
    f[1] = make_float4(bu2f(a0.z), bu2f(a0.z >> 16), bu2f(a0.w), bu2f(a0.w >> 16));
    f[2] = make_float4(bu2f(a1.x), bu2f(a1.x >> 16), bu2f(a1.y), bu2f(a1.y >> 16));
    f[3] = make_float4(bu2f(a1.z), bu2f(a1.z >> 16), bu2f(a1.w), bu2f(a1.w >> 16));
    float4* g = (float4*)&lv[r][q4 * 16];
    g[0] = make_float4(bu2f(b0.x), bu2f(b0.x >> 16), bu2f(b0.y), bu2f(b0.y >> 16));
    g[1] = make_float4(bu2f(b0.z), bu2f(b0.z >> 16), bu2f(b0.w), bu2f(b0.w >> 16));
    g[2] = make_float4(bu2f(b1.x), bu2f(b1.x >> 16), bu2f(b1.y), bu2f(b1.y >> 16));
    g[3] = make_float4(bu2f(b1.z), bu2f(b1.z >> 16), bu2f(b1.w), bu2f(b1.w >> 16));
  }
  __syncthreads();

  int n = r, db = q4 * 16;
  float acc[16];
#pragma unroll
  for (int i = 0; i < 16; ++i) acc[i] = 0.f;
  for (int m = 0; m < 64; ++m) {
    float p = lP[n][m];
    const float4* vp = (const float4*)&lv[m][db];
    float4 v0 = vp[0], v1 = vp[1], v2 = vp[2], v3 = vp[3];
    acc[0] += p * v0.x; acc[1] += p * v0.y; acc[2] += p * v0.z; acc[3] += p * v0.w;
    acc[4] += p * v1.x; acc[5] += p * v1.y; acc[6] += p * v1.z; acc[7] += p * v1.w;
    acc[8] += p * v2.x; acc[9] += p * v2.y; acc[10] += p * v2.z; acc[11] += p * v2.w;
    acc[12] += p * v3.x; acc[13] += p * v3.y; acc[14] += p * v3.z; acc[15] += p * v3.w;
  }
  uint4 o0, o1;
  o0.x = pk2(acc[0], acc[1]); o0.y = pk2(acc[2], acc[3]);
  o0.z = pk2(acc[4], acc[5]); o0.w = pk2(acc[6], acc[7]);
  o1.x = pk2(acc[8], acc[9]); o1.y = pk2(acc[10], acc[11]);
  o1.z = pk2(acc[12], acc[13]); o1.w = pk2(acc[14], acc[15]);
  u16* dst = Ob + ((size_t)(win * 64 + n)) * 512 + h * 64 + db;
  *(uint4*)dst = o0; *(uint4*)(dst + 8) = o1;
}

// ---------------------------------------------------------------------------
extern "C" void kernel_launch(void* const* d_in, const int* in_sizes, int n_in,
                              void* d_out, int out_size, void* d_ws, size_t ws_size,
                              hipStream_t stream) {
  (void)in_sizes; (void)n_in; (void)out_size; (void)ws_size;
  const float* xin[3] = {(const float*)d_in[0], (const float*)d_in[1], (const float*)d_in[2]};
  const float* bq = (const float*)d_in[4];
  const float* bk = (const float*)d_in[6];
  const float* bv[3] = {(const float*)d_in[8], (const float*)d_in[10], (const float*)d_in[12]};
  const float* bp[3] = {(const float*)d_in[14], (const float*)d_in[16], (const float*)d_in[18]};
  const float* rpb = (const float*)d_in[19];
  const float* b1[3] = {(const float*)d_in[21], (const float*)d_in[25], (const float*)d_in[29]};
  const float* b2[3] = {(const float*)d_in[23], (const float*)d_in[27], (const float*)d_in[31]};
  float* dout = (float*)d_out;
  u16* wsb = (u16*)d_ws;

  // weight transpose+cast jobs: {src d_in idx, dst elem off, K, N}
  const int   tsrc[14] = {3, 5, 7, 9, 11, 13, 15, 17, 20, 24, 28, 22, 26, 30};
  const size_t tdst[14] = {0, 262144, 524288, 786432, 1048576, 1310720, 1572864, 1835008,
                           2097152, 3145728, 4194304, 5242880, 6291456, 7340032};
  const int   tK[14] = {512, 512, 512, 512, 512, 512, 512, 512, 512, 512, 512, 2048, 2048, 2048};
  const int   tN[14] = {512, 512, 512, 512, 512, 512, 512, 512, 2048, 2048, 2048, 512, 512, 512};
  for (int i = 0; i < 14; ++i)
    transpose_cvt<<<dim3(tN[i] / 32, tK[i] / 32), dim3(32, 8), 0, stream>>>(
        (const float*)d_in[tsrc[i]], wsb + tdst[i], tK[i], tN[i]);

  u16* Wqk = wsb;                                        // 1024 x 512 (q rows 0..511)
  u16* Wv[3] = {wsb + 524288, wsb + 786432, wsb + 1048576};
  u16* Wp[3] = {wsb + 1310720, wsb + 1572864, wsb + 1835008};
  u16* W1[3] = {wsb + 2097152, wsb + 3145728, wsb + 4194304};
  u16* W2[3] = {wsb + 5242880, wsb + 6291456, wsb + 7340032};
  u16* Qb = wsb + 8388608;
  u16* Kb = wsb + 41943040;
  u16* Pb = wsb + 75497472;
  u16* Vb = Qb;                                          // V reuses Q region
  u16* Ob = Kb;                                          // O reuses K region
  u16* Yb = Qb;                                          // bf16 (x+attn) reuses V region
  u16* Hb = Kb;                                          // hidden chunk reuses O region

  // Q,K projection (gathered fp32 input, N=1024)
  gemm_k<0, 0, 8><<<4096, 256, 0, stream>>>(xin[0], 512, Wqk, 512, bq, bk,
                                            nullptr, nullptr, Qb, Kb, 0);
  // softmax(q k^T + rpb + mask)
  attn_softmax<<<dim3(8192), 256, 0, stream>>>(Qb, Kb, rpb, Pb);

  // per-stream: V proj, O = P V, out-proj (+bf16 Y), then MLP in 4 row-chunks
  for (int s = 0; s < 3; ++s) {
    gemm_k<0, 1, 4><<<2048, 256, 0, stream>>>(xin[s], 512, Wv[s], 512, bv[s],
                                              nullptr, nullptr, nullptr, Vb, nullptr, 0);
    attn_av<<<dim3(8192), 256, 0, stream>>>(Pb, Vb, Ob);
    gemm_k<2, 2, 4><<<2048, 256, 0, stream>>>(Ob, 512, Wp[s], 512, bp[s], nullptr,
                                              xin[s], dout + (size_t)s * 33554432,
                                              Yb, nullptr, 0);
    for (int c = 0; c < 4; ++c) {
      const u16* Ac = Yb + (size_t)c * 8388608;          // 16384 rows x 512
      gemm_k<2, 3, 16><<<2048, 256, 0, stream>>>(Ac, 512, W1[s], 512, b1[s],
                                                 nullptr, nullptr, nullptr, Hb, nullptr, 0);
      gemm_k<2, 4, 4><<<512, 256, 0, stream>>>(Hb, 2048, W2[s], 2048, b2[s],
                                               nullptr, nullptr,
                                               dout + (size_t)s * 33554432,
                                               nullptr, nullptr, c * 16384);
    }
  }
}